// Round 12
// baseline (241.486 us; speedup 1.0000x reference)
//
#include <hip/hip_runtime.h>
#include <math.h>

#define BB 8
#define FF 256
#define SS 1024
#define KK 16
#define ITERS 5
#define NG 64              // 16-row groups per batch (1024/16)

typedef unsigned long long ull;

__device__ __forceinline__ ull umin64(ull a, ull b) { return a < b ? a : b; }

// ---------- d[b][i][j] = sum_f |x[b][f][i] - x[b][f][j]|  (+ fused wm) ----------
// Tile path (blockIdx.x < 264): 32x32 wave-private tiles, 2 independent waves
// per block, 8 KB/block, FCD=8 double-buffered global->LDS staging (vmcnt(2)).
// __launch_bounds__(128,4): 128-VGPR cap, 48 used -> no spill (R8 lesson).
// f ascending (bitwise-matches all passing versions). [R9/R11-measured: 94 us]
// wm path (blockIdx.x >= 264): 4 blocks x 128 thr per batch compute
// wm[b][j] = mean_i w[b][i][j] with the SAME FP order as the old two-stage
// version (8 sequential partials of 128 rows, partials summed ascending) —
// runs hidden under the tile blocks.
#define FCD 8
__device__ __forceinline__ void async_copy16(const float* g, const float* s) {
    __builtin_amdgcn_global_load_lds((const __attribute__((address_space(1))) void*)g,
                                     (__attribute__((address_space(3))) void*)s, 16, 0, 0);
}

__global__ __launch_bounds__(128, 4) void dist_kernel(const float* __restrict__ x,
                                                      float* __restrict__ d,
                                                      const float* __restrict__ wfull,
                                                      float* __restrict__ wm) {
    int b = blockIdx.y;
    if (blockIdx.x >= 264) {
        // ---- wm path: 512 threads/batch, 2 columns each ----
        int gthr = (blockIdx.x - 264) * 128 + threadIdx.x;   // 0..511
        const float* wb = wfull + (size_t)b * SS * SS;
#pragma unroll
        for (int h = 0; h < 2; ++h) {
            int j = gthr + h * 512;
            const float* col = wb + j;
            float tot = 0.f;
            for (int ic = 0; ic < 8; ++ic) {
                float p = 0.f;
#pragma unroll 16
                for (int i = 0; i < 128; ++i) p += col[(size_t)(ic * 128 + i) * SS];
                tot += p;
            }
            wm[b * SS + j] = tot * (1.0f / SS);
        }
        return;
    }
    __shared__ float smem[2048];   // per wave (1024): A0 256|B0 256|A1 256|B1 256
    int tid = threadIdx.x;
    int wave = tid >> 6, lane = tid & 63;
    int tw = blockIdx.x * 2 + wave;     // 0..527 triangular tile id (32x32 tiles)
    int it = 0, rem = tw;
    while (rem >= 32 - it) { rem -= 32 - it; ++it; }
    int jt = it + rem;
    int i0 = it * 32, j0 = jt * 32;
    const float* xb = x + (size_t)b * FF * SS;
    float* db = d + (size_t)b * SS * SS;
    float* wbase = smem + wave * 1024;
    int ly = lane >> 3, lx = lane & 7;           // 8x8 lane grid, 4x4 each
    int sFl = lane >> 3, sTk = (lane & 7) * 4;   // staging: 8 f-rows x 32 tok/inst

    float acc[4][4] = {};

    auto stage = [&](int c, int h) {
        float* A = wbase + h * 512;
        const float* base = xb + (size_t)c * FCD * SS + (size_t)sFl * SS;
        async_copy16(base + i0 + sTk, A);          // A chunk: 8f x 32tok = 1 inst
        async_copy16(base + j0 + sTk, A + 256);    // B chunk
    };
    auto compute = [&](int h) {
        const float* A = wbase + h * 512;
        const float* B = A + 256;
#pragma unroll
        for (int f = 0; f < FCD; ++f) {
            float4 a = *(const float4*)(A + f * 32 + ly * 4);
            float4 bb = *(const float4*)(B + f * 32 + lx * 4);
            float av[4] = {a.x, a.y, a.z, a.w};
            float bv[4] = {bb.x, bb.y, bb.z, bb.w};
#pragma unroll
            for (int r = 0; r < 4; ++r)
#pragma unroll
                for (int c = 0; c < 4; ++c)
                    acc[r][c] += fabsf(av[r] - bv[c]);
        }
    };

    stage(0, 0);
#pragma unroll 1
    for (int k = 0; k < FF / FCD - 1; ++k) {
        // WAR: ds_reads of the buffer we are about to overwrite have retired
        asm volatile("s_waitcnt lgkmcnt(0)" ::: "memory");
        stage(k + 1, (k + 1) & 1);
        // wait only for chunk k's 2 loads; chunk k+1's 2 stay in flight
        asm volatile("s_waitcnt vmcnt(2)" ::: "memory");
        compute(k & 1);
    }
    asm volatile("s_waitcnt vmcnt(0)" ::: "memory");
    compute(1);   // chunk 31 -> buffer 1

    // direct tile: rows i0+ly*4+r, cols j0+lx*4
#pragma unroll
    for (int r = 0; r < 4; ++r) {
        float4 v = make_float4(acc[r][0], acc[r][1], acc[r][2], acc[r][3]);
        *(float4*)&db[(size_t)(i0 + ly * 4 + r) * SS + j0 + lx * 4] = v;
    }
    if (it != jt) {
        // mirror straight from registers (d bitwise symmetric)
#pragma unroll
        for (int c = 0; c < 4; ++c) {
            float4 v = make_float4(acc[0][c], acc[1][c], acc[2][c], acc[3][c]);
            *(float4*)&db[(size_t)(j0 + lx * 4 + c) * SS + i0 + ly * 4] = v;
        }
    }
}

// ---------- topk (jax.lax.top_k semantics) -> seeds part0 ----------
// wm > 0 strictly (means of uniform[0,1)), so float bits are order-monotonic.
// part layout: part[t][b][k][g] packed u64 (costbits<<32|idx); decode = min
// over g (order-independent). topk writes part0[b][k][0] = (0|ctr0[k]) and
// ~0ull elsewhere (re-inits every call; ws is poisoned).
__global__ __launch_bounds__(1024) void topk_kernel(const float* __restrict__ wm,
                                                    ull* __restrict__ part0) {
    int b = blockIdx.x;
    int tid = threadIdx.x;          // == token index
    int lane = tid & 63, wv = tid >> 6;
    __shared__ ull red[16];
    __shared__ int ctr_s[KK];
    float v = wm[b * SS + tid];
    // key: value-desc, tie -> smaller index (complemented idx, max-reduce)
    ull key = (((ull)__float_as_uint(v)) << 32) | (ull)(0xFFFFFFFFu - (unsigned)tid);
    for (int k = 0; k < KK; ++k) {
        ull kk = key;
#pragma unroll
        for (int off = 32; off; off >>= 1) {
            ull o = __shfl_down(kk, off, 64);
            if (o > kk) kk = o;
        }
        if (lane == 0) red[wv] = kk;
        __syncthreads();
        if (wv == 0) {
            ull k2 = (lane < 16) ? red[lane] : 0ull;
#pragma unroll
            for (int off = 8; off; off >>= 1) {
                ull o = __shfl_down(k2, off, 64);
                if (o > k2) k2 = o;
            }
            if (lane == 0) red[0] = k2;
        }
        __syncthreads();
        ull W = red[0];
        int widx = (int)(0xFFFFFFFFu - (unsigned)(W & 0xFFFFFFFFu));
        if (tid == widx) key = 0;            // remove winner
        if (tid == 0) ctr_s[k] = widx;
        __syncthreads();                      // protect red[] before next round
    }
    // seed part0: tid covers (k = tid>>6, g = tid&63)
    int k = tid >> 6, g = tid & 63;
    part0[((size_t)b * KK + k) * NG + g] =
        (g == 0) ? (ull)(unsigned)ctr_s[k] : ~0ull;
}

// ---------- one full k-medoids iteration, single dispatch ----------
// 512 blocks (64 row-groups x 8 batches), 256 threads:
//  1) decode ctr from pprev (min over 64 partials per cluster; ~0ull -> 0)
//  2) recompute assign[j] for ALL j redundantly (packed-key min over 16
//     medoid rows: smallest dist, tie -> smallest k == strict-< ascending k)
//  3) cost for this block's 16 rows (FP order bitwise = R11's passing cost)
//  4) per-cluster block-minimum -> pnext (plain stores, no atomics;
//     next dispatch's min-reduce is order-independent => deterministic)
__global__ __launch_bounds__(256) void iter_kernel(const float* __restrict__ d,
                                                   const float* __restrict__ wm,
                                                   const ull* __restrict__ pprev,
                                                   ull* __restrict__ pnext) {
    int b = blockIdx.y, g = blockIdx.x;
    int tid = threadIdx.x;
    int lane = tid & 63, wv = tid >> 6;
    __shared__ float wmv[SS];        // 4 KB
    __shared__ int asg[SS];          // 4 KB
    __shared__ int ctr_s[KK];
    __shared__ ull m16[KK][17];      // padded
    __shared__ ull rowkey[16];
    // load wm
    *(float4*)&wmv[tid * 4] = *(const float4*)&wm[b * SS + tid * 4];
    // decode ctr: 16 threads/cluster scan 4 partials each, then reduce 16
    {
        int k = tid >> 4, s = tid & 15;
        const ull* pp = &pprev[((size_t)b * KK + k) * NG + s * 4];
        ull m = umin64(umin64(pp[0], pp[1]), umin64(pp[2], pp[3]));
        m16[k][s] = m;
    }
    __syncthreads();
    if (tid < KK) {
        ull m = m16[tid][0];
#pragma unroll
        for (int s = 1; s < 16; ++s) m = umin64(m, m16[tid][s]);
        ctr_s[tid] = (m == ~0ull) ? 0 : (int)(m & 0xFFFFFFFFu);
    }
    __syncthreads();
    // assign all 1024 tokens (coalesced over tid for each medoid row)
    const float* db = d + (size_t)b * SS * SS;
#pragma unroll
    for (int t = 0; t < 4; ++t) {
        int j = t * 256 + tid;
        ull bk = ~0ull;
#pragma unroll
        for (int k = 0; k < KK; ++k) {
            float vv = db[(size_t)ctr_s[k] * SS + j];
            ull key = (((ull)__float_as_uint(vv)) << 32) | (unsigned)k;
            if (key < bk) bk = key;
        }
        asg[j] = (int)(bk & 0xFFFFFFFFu);
    }
    __syncthreads();
    // cost rows g*16 + wv*4 + r  (cost >= 0 finite -> bits order-monotonic)
#pragma unroll
    for (int r = 0; r < 4; ++r) {
        int i = g * 16 + wv * 4 + r;
        int my = asg[i];
        const float* drow = db + (size_t)i * SS;
        float s = 0.f;
#pragma unroll
        for (int c = 0; c < 4; ++c) {
            int j = c * 256 + lane * 4;
            float4 dv = *(const float4*)&drow[j];
            float4 w4 = *(const float4*)&wmv[j];
            int4 a4 = *(const int4*)&asg[j];
            s += (a4.x == my) ? dv.x * w4.x : 0.f;
            s += (a4.y == my) ? dv.y * w4.y : 0.f;
            s += (a4.z == my) ? dv.z * w4.z : 0.f;
            s += (a4.w == my) ? dv.w * w4.w : 0.f;
        }
#pragma unroll
        for (int off = 32; off; off >>= 1) s += __shfl_down(s, off, 64);
        if (lane == 0)
            rowkey[wv * 4 + r] = (((ull)__float_as_uint(s)) << 32) | (unsigned)i;
    }
    __syncthreads();
    // per-cluster block minimum over the 16 rows -> pnext
    if (tid < KK) {
        ull m = ~0ull;
#pragma unroll
        for (int r = 0; r < 16; ++r)
            if (asg[g * 16 + r] == tid) m = umin64(m, rowkey[r]);
        pnext[((size_t)b * KK + tid) * NG + g] = m;
    }
}

// ---------- final gather: decode part5, out[b][f][k] = x[b][f][ctr[k]] ----------
__global__ __launch_bounds__(256) void gather_kernel(const float* __restrict__ x,
                                                     const ull* __restrict__ pfin,
                                                     float* __restrict__ out) {
    int b = blockIdx.y, q = blockIdx.x;   // quarter 0..3
    int tid = threadIdx.x;
    __shared__ ull m16[KK][17];
    __shared__ int ctr_s[KK];
    {
        int k = tid >> 4, s = tid & 15;
        const ull* pp = &pfin[((size_t)b * KK + k) * NG + s * 4];
        ull m = umin64(umin64(pp[0], pp[1]), umin64(pp[2], pp[3]));
        m16[k][s] = m;
    }
    __syncthreads();
    if (tid < KK) {
        ull m = m16[tid][0];
#pragma unroll
        for (int s = 1; s < 16; ++s) m = umin64(m, m16[tid][s]);
        ctr_s[tid] = (m == ~0ull) ? 0 : (int)(m & 0xFFFFFFFFu);
    }
    __syncthreads();
#pragma unroll
    for (int t = 0; t < 4; ++t) {
        int e = q * 1024 + t * 256 + tid;   // FF*KK = 4096 per batch
        int f = e >> 4, k = e & 15;
        out[((size_t)b * FF + f) * KK + k] = x[((size_t)b * FF + f) * SS + ctr_s[k]];
    }
}

extern "C" void kernel_launch(void* const* d_in, const int* in_sizes, int n_in,
                              void* d_out, int out_size, void* d_ws, size_t ws_size,
                              hipStream_t stream) {
    const float* x = (const float*)d_in[0];   // [B,F,S]
    const float* w = (const float*)d_in[1];   // [B,S,S]
    float* out = (float*)d_out;               // [B,F,K]

    char* ws = (char*)d_ws;
    float* d = (float*)ws;                              // B*S*S floats = 33.55 MB
    size_t off = (size_t)BB * SS * SS * sizeof(float);
    float* wm = (float*)(ws + off);   off += (size_t)BB * SS * sizeof(float);
    off = (off + 15) & ~(size_t)15;
    ull* part = (ull*)(ws + off);     // [ITERS+1][B][K][NG] packed partials (384 KB)
    const size_t PST = (size_t)BB * KK * NG;

    // tiles (264) + wm blocks (4) per batch in one dispatch
    dist_kernel<<<dim3(268, BB), 128, 0, stream>>>(x, d, w, wm);
    topk_kernel<<<BB, 1024, 0, stream>>>(wm, part);
    for (int t = 1; t <= ITERS; ++t)
        iter_kernel<<<dim3(NG, BB), 256, 0, stream>>>(d, wm, part + (t - 1) * PST,
                                                      part + t * PST);
    gather_kernel<<<dim3(4, BB), 256, 0, stream>>>(x, part + ITERS * PST, out);
}

// Round 13
// 235.442 us; speedup vs baseline: 1.0257x; 1.0257x over previous
//
#include <hip/hip_runtime.h>
#include <math.h>

#define BB 8
#define FF 256
#define SS 1024
#define KK 16
#define ITERS 5
#define NG 64              // 16-row groups per batch (1024/16)

typedef unsigned long long ull;

__device__ __forceinline__ ull umin64(ull a, ull b) { return a < b ? a : b; }

// ---------- wm stage 1: partial column sums of w ----------
#define ICH 8
__global__ void wm_part_kernel(const float* __restrict__ w, float* __restrict__ part) {
    int j = blockIdx.x * 256 + threadIdx.x;
    int ic = blockIdx.y, b = blockIdx.z;
    const float* wp = w + (size_t)b * SS * SS + (size_t)ic * (SS / ICH) * SS + j;
    float s = 0.f;
#pragma unroll 16
    for (int i = 0; i < SS / ICH; ++i) s += wp[(size_t)i * SS];
    part[((size_t)ic * BB + b) * SS + j] = s;
}

// ---------- d[b][i][j] = sum_f |x[b][f][i] - x[b][f][j]| ----------
// 32x32 wave-private tiles, 2 independent waves per block, 8 KB/block,
// FCD=8 double-buffered global->LDS staging (vmcnt(2)).
// __launch_bounds__(128,4): 128-VGPR cap, 48 used -> no spill (R8 lesson:
// (128,8)'s 64-cap spilled acc, WRITE_SIZE 241 MB). PURE dist — R12's
// wm-fusion made its blocks stragglers (+49 us). [R9/R11-measured: 94 us]
// f ascending (bitwise-matches all passing versions).
#define FCD 8
__device__ __forceinline__ void async_copy16(const float* g, const float* s) {
    __builtin_amdgcn_global_load_lds((const __attribute__((address_space(1))) void*)g,
                                     (__attribute__((address_space(3))) void*)s, 16, 0, 0);
}

__global__ __launch_bounds__(128, 4) void dist_kernel(const float* __restrict__ x,
                                                      float* __restrict__ d) {
    __shared__ float smem[2048];   // per wave (1024): A0 256|B0 256|A1 256|B1 256
    int tid = threadIdx.x;
    int wave = tid >> 6, lane = tid & 63;
    int b = blockIdx.y;
    int w = blockIdx.x * 2 + wave;      // 0..527 triangular tile id (32x32 tiles)
    int it = 0, rem = w;
    while (rem >= 32 - it) { rem -= 32 - it; ++it; }
    int jt = it + rem;
    int i0 = it * 32, j0 = jt * 32;
    const float* xb = x + (size_t)b * FF * SS;
    float* db = d + (size_t)b * SS * SS;
    float* wbase = smem + wave * 1024;
    int ly = lane >> 3, lx = lane & 7;           // 8x8 lane grid, 4x4 each
    int sFl = lane >> 3, sTk = (lane & 7) * 4;   // staging: 8 f-rows x 32 tok/inst

    float acc[4][4] = {};

    auto stage = [&](int c, int h) {
        float* A = wbase + h * 512;
        const float* base = xb + (size_t)c * FCD * SS + (size_t)sFl * SS;
        async_copy16(base + i0 + sTk, A);          // A chunk: 8f x 32tok = 1 inst
        async_copy16(base + j0 + sTk, A + 256);    // B chunk
    };
    auto compute = [&](int h) {
        const float* A = wbase + h * 512;
        const float* B = A + 256;
#pragma unroll
        for (int f = 0; f < FCD; ++f) {
            float4 a = *(const float4*)(A + f * 32 + ly * 4);
            float4 bb = *(const float4*)(B + f * 32 + lx * 4);
            float av[4] = {a.x, a.y, a.z, a.w};
            float bv[4] = {bb.x, bb.y, bb.z, bb.w};
#pragma unroll
            for (int r = 0; r < 4; ++r)
#pragma unroll
                for (int c = 0; c < 4; ++c)
                    acc[r][c] += fabsf(av[r] - bv[c]);
        }
    };

    stage(0, 0);
#pragma unroll 1
    for (int k = 0; k < FF / FCD - 1; ++k) {
        // WAR: ds_reads of the buffer we are about to overwrite have retired
        asm volatile("s_waitcnt lgkmcnt(0)" ::: "memory");
        stage(k + 1, (k + 1) & 1);
        // wait only for chunk k's 2 loads; chunk k+1's 2 stay in flight
        asm volatile("s_waitcnt vmcnt(2)" ::: "memory");
        compute(k & 1);
    }
    asm volatile("s_waitcnt vmcnt(0)" ::: "memory");
    compute(1);   // chunk 31 -> buffer 1

    // direct tile: rows i0+ly*4+r, cols j0+lx*4
#pragma unroll
    for (int r = 0; r < 4; ++r) {
        float4 v = make_float4(acc[r][0], acc[r][1], acc[r][2], acc[r][3]);
        *(float4*)&db[(size_t)(i0 + ly * 4 + r) * SS + j0 + lx * 4] = v;
    }
    if (it != jt) {
        // mirror straight from registers (d bitwise symmetric)
#pragma unroll
        for (int c = 0; c < 4; ++c) {
            float4 v = make_float4(acc[0][c], acc[1][c], acc[2][c], acc[3][c]);
            *(float4*)&db[(size_t)(j0 + lx * 4 + c) * SS + i0 + ly * 4] = v;
        }
    }
}

// ---------- wm finalize + topk (jax.lax.top_k) -> seeds part0 ----------
// wm > 0 strictly (means of uniform[0,1)), so float bits are order-monotonic.
// part0 layout: [b][k][g] packed u64 (costbits<<32|idx); decode = min over g
// (order-independent). topk writes part0[b][k][0] = (0|ctr0[k]), ~0ull else
// (re-inits every call; ws is poisoned between calls).
__global__ __launch_bounds__(1024) void topk_kernel(const float* __restrict__ wpart,
                                                    float* __restrict__ wm,
                                                    ull* __restrict__ part0) {
    int b = blockIdx.x;
    int tid = threadIdx.x;          // == token index
    int lane = tid & 63, wv = tid >> 6;
    __shared__ ull red[16];
    __shared__ int ctr_s[KK];
    // finalize wm for this batch (ascending-ic order, as measured-good)
    float v = 0.f;
#pragma unroll
    for (int ic = 0; ic < ICH; ++ic) v += wpart[((size_t)ic * BB + b) * SS + tid];
    v *= (1.0f / SS);
    wm[b * SS + tid] = v;
    // key: value-desc, tie -> smaller index (complemented idx, max-reduce)
    ull key = (((ull)__float_as_uint(v)) << 32) | (ull)(0xFFFFFFFFu - (unsigned)tid);
    for (int k = 0; k < KK; ++k) {
        ull kk = key;
#pragma unroll
        for (int off = 32; off; off >>= 1) {
            ull o = __shfl_down(kk, off, 64);
            if (o > kk) kk = o;
        }
        if (lane == 0) red[wv] = kk;
        __syncthreads();
        if (wv == 0) {
            ull k2 = (lane < 16) ? red[lane] : 0ull;
#pragma unroll
            for (int off = 8; off; off >>= 1) {
                ull o = __shfl_down(k2, off, 64);
                if (o > k2) k2 = o;
            }
            if (lane == 0) red[0] = k2;
        }
        __syncthreads();
        ull W = red[0];
        int widx = (int)(0xFFFFFFFFu - (unsigned)(W & 0xFFFFFFFFu));
        if (tid == widx) key = 0;            // remove winner
        if (tid == 0) ctr_s[k] = widx;
        __syncthreads();                      // protect red[] before next round
    }
    // seed part0: tid covers (k = tid>>6, g = tid&63)
    int k = tid >> 6, g = tid & 63;
    part0[((size_t)b * KK + k) * NG + g] =
        (g == 0) ? (ull)(unsigned)ctr_s[k] : ~0ull;
}

// ---------- one full k-medoids iteration, single dispatch ----------
// 512 blocks (64 row-groups x 8 batches), 256 threads:
//  1) decode ctr from pprev (min over 64 partials per cluster; ~0ull -> 0)
//  2) recompute assign[j] for ALL j redundantly (packed-key min over 16
//     medoid rows: smallest dist, tie -> smallest k == strict-< ascending k)
//  3) cost for this block's 16 rows
//  4) per-cluster block-minimum -> pnext (plain stores, no atomics, no
//     fences — next dispatch's min-reduce is order-independent)
__global__ __launch_bounds__(256) void iter_kernel(const float* __restrict__ d,
                                                   const float* __restrict__ wm,
                                                   const ull* __restrict__ pprev,
                                                   ull* __restrict__ pnext) {
    int b = blockIdx.y, g = blockIdx.x;
    int tid = threadIdx.x;
    int lane = tid & 63, wv = tid >> 6;
    __shared__ float wmv[SS];        // 4 KB
    __shared__ int asg[SS];          // 4 KB
    __shared__ int ctr_s[KK];
    __shared__ ull m16[KK][17];      // padded
    __shared__ ull rowkey[16];
    // load wm
    *(float4*)&wmv[tid * 4] = *(const float4*)&wm[b * SS + tid * 4];
    // decode ctr: 16 threads/cluster scan 4 partials each, then reduce 16
    {
        int k = tid >> 4, s = tid & 15;
        const ull* pp = &pprev[((size_t)b * KK + k) * NG + s * 4];
        ull m = umin64(umin64(pp[0], pp[1]), umin64(pp[2], pp[3]));
        m16[k][s] = m;
    }
    __syncthreads();
    if (tid < KK) {
        ull m = m16[tid][0];
#pragma unroll
        for (int s = 1; s < 16; ++s) m = umin64(m, m16[tid][s]);
        ctr_s[tid] = (m == ~0ull) ? 0 : (int)(m & 0xFFFFFFFFu);
    }
    __syncthreads();
    // assign all 1024 tokens (coalesced over tid for each medoid row)
    const float* db = d + (size_t)b * SS * SS;
#pragma unroll
    for (int t = 0; t < 4; ++t) {
        int j = t * 256 + tid;
        ull bk = ~0ull;
#pragma unroll
        for (int k = 0; k < KK; ++k) {
            float vv = db[(size_t)ctr_s[k] * SS + j];
            ull key = (((ull)__float_as_uint(vv)) << 32) | (unsigned)k;
            if (key < bk) bk = key;
        }
        asg[j] = (int)(bk & 0xFFFFFFFFu);
    }
    __syncthreads();
    // cost rows g*16 + wv*4 + r  (cost >= 0 finite -> bits order-monotonic)
#pragma unroll
    for (int r = 0; r < 4; ++r) {
        int i = g * 16 + wv * 4 + r;
        int my = asg[i];
        const float* drow = db + (size_t)i * SS;
        float s = 0.f;
#pragma unroll
        for (int c = 0; c < 4; ++c) {
            int j = c * 256 + lane * 4;
            float4 dv = *(const float4*)&drow[j];
            float4 w4 = *(const float4*)&wmv[j];
            int4 a4 = *(const int4*)&asg[j];
            s += (a4.x == my) ? dv.x * w4.x : 0.f;
            s += (a4.y == my) ? dv.y * w4.y : 0.f;
            s += (a4.z == my) ? dv.z * w4.z : 0.f;
            s += (a4.w == my) ? dv.w * w4.w : 0.f;
        }
#pragma unroll
        for (int off = 32; off; off >>= 1) s += __shfl_down(s, off, 64);
        if (lane == 0)
            rowkey[wv * 4 + r] = (((ull)__float_as_uint(s)) << 32) | (unsigned)i;
    }
    __syncthreads();
    // per-cluster block minimum over the 16 rows -> pnext
    if (tid < KK) {
        ull m = ~0ull;
#pragma unroll
        for (int r = 0; r < 16; ++r)
            if (asg[g * 16 + r] == tid) m = umin64(m, rowkey[r]);
        pnext[((size_t)b * KK + tid) * NG + g] = m;
    }
}

// ---------- final gather: decode part5, out[b][f][k] = x[b][f][ctr[k]] ----------
__global__ __launch_bounds__(256) void gather_kernel(const float* __restrict__ x,
                                                     const ull* __restrict__ pfin,
                                                     float* __restrict__ out) {
    int b = blockIdx.y, q = blockIdx.x;   // quarter 0..3
    int tid = threadIdx.x;
    __shared__ ull m16[KK][17];
    __shared__ int ctr_s[KK];
    {
        int k = tid >> 4, s = tid & 15;
        const ull* pp = &pfin[((size_t)b * KK + k) * NG + s * 4];
        ull m = umin64(umin64(pp[0], pp[1]), umin64(pp[2], pp[3]));
        m16[k][s] = m;
    }
    __syncthreads();
    if (tid < KK) {
        ull m = m16[tid][0];
#pragma unroll
        for (int s = 1; s < 16; ++s) m = umin64(m, m16[tid][s]);
        ctr_s[tid] = (m == ~0ull) ? 0 : (int)(m & 0xFFFFFFFFu);
    }
    __syncthreads();
#pragma unroll
    for (int t = 0; t < 4; ++t) {
        int e = q * 1024 + t * 256 + tid;   // FF*KK = 4096 per batch
        int f = e >> 4, k = e & 15;
        out[((size_t)b * FF + f) * KK + k] = x[((size_t)b * FF + f) * SS + ctr_s[k]];
    }
}

extern "C" void kernel_launch(void* const* d_in, const int* in_sizes, int n_in,
                              void* d_out, int out_size, void* d_ws, size_t ws_size,
                              hipStream_t stream) {
    const float* x = (const float*)d_in[0];   // [B,F,S]
    const float* w = (const float*)d_in[1];   // [B,S,S]
    float* out = (float*)d_out;               // [B,F,K]

    char* ws = (char*)d_ws;
    float* d = (float*)ws;                              // B*S*S floats = 33.55 MB
    size_t off = (size_t)BB * SS * SS * sizeof(float);
    float* wm = (float*)(ws + off);    off += (size_t)BB * SS * sizeof(float);
    off = (off + 15) & ~(size_t)15;
    ull* part = (ull*)(ws + off);      off += (size_t)(ITERS + 1) * BB * KK * NG * sizeof(ull);
    float* wpart = (float*)(ws + off); // [ICH][B][S] = 256 KB
    const size_t PST = (size_t)BB * KK * NG;

    wm_part_kernel<<<dim3(SS / 256, ICH, BB), 256, 0, stream>>>(w, wpart);
    // 528 triangular 32x32 wave-tiles per batch, 2 waves (2 tiles) per block
    dist_kernel<<<dim3(264, BB), 128, 0, stream>>>(x, d);
    topk_kernel<<<BB, 1024, 0, stream>>>(wpart, wm, part);
    for (int t = 1; t <= ITERS; ++t)
        iter_kernel<<<dim3(NG, BB), 256, 0, stream>>>(d, wm, part + (t - 1) * PST,
                                                      part + t * PST);
    gather_kernel<<<dim3(4, BB), 256, 0, stream>>>(x, part + ITERS * PST, out);
}